// Round 15
// baseline (57.873 us; speedup 1.0000x reference)
//
#include <hip/hip_runtime.h>
#include <hip/hip_bf16.h>

// Fused 3x3 valid conv, fp32 NCHW in -> fp32 NCHW out, bf16 MFMA inside.
// x: (16,32,256,256) f32; w: (32,32,3,3) f32; out: (16,32,254,254) f32.
//
// Block = 512 thr (8 waves) = 128 out-px (half width) x 16 out-rows x 32 co.
// Input: 8-slot LDS ring, reg-staged (float4 + v_cvt_pk_bf16_f32 + b128).
// R15: OUTPUT TRANSPOSE THROUGH LDS -- acc rows go to Lout[co][px] (pad 132,
// conflict-free b128 writes), then each wave stores 4 co-planes as 512B
// CONTIGUOUS runs (vs 64B x 16-plane scatter before). 2 lgkm-barriers/step.

typedef __attribute__((ext_vector_type(8))) short bf16x8;
typedef __attribute__((ext_vector_type(4))) float f32x4;

#define MFMA(a,b,c) __builtin_amdgcn_mfma_f32_16x16x32_bf16((a),(b),(c),0,0,0)
#define SCHED0 __builtin_amdgcn_sched_barrier(0)
#define LGKMBAR asm volatile("s_waitcnt lgkmcnt(0)\n\ts_barrier" ::: "memory")

__device__ __forceinline__ unsigned short f2bf(float f) {
    unsigned int u = __float_as_uint(f);
    return (unsigned short)((u + 0x7FFFu + ((u >> 16) & 1u)) >> 16);   // RNE
}
__device__ __forceinline__ unsigned int packpair(float a, float b) {
    __hip_bfloat162 t = __float22bfloat162_rn(make_float2(a, b));      // v_cvt_pk_bf16_f32
    union { __hip_bfloat162 h; unsigned int u; } c;
    c.h = t;
    return c.u;
}

// LDS: input ring = 8 slots x (16 ci2-rows x 132 u32) = 67584 B.
// Lout = 2 row-buffers x 32 co x 132 f32 (528 B/co, 16B-mult) = 33792 B.
// Total 101376 B.
#define ROWW 132
#define SLOTW (16 * ROWW)
#define LOUT0 (8 * SLOTW)          // u32 offset of Lout
#define LOUTROW (32 * ROWW)        // u32 per Lout row-buffer

#define ROWCL(R_) ((R0 + (R_)) > 255 ? 255 : (R0 + (R_)))

// issue global loads for input row R (3-deep reg ring, literal %3)
#define ISSUE(R_) do {                                                       \
    const float* rp_ = xim + ((size_t)ROWCL(R_) << 8) + gpx;                 \
    gA[(R_) % 3] = *(const float4*)(rp_ + ((size_t)pA << 16));               \
    gB[(R_) % 3] = *(const float4*)(rp_ + (((size_t)pA + 1) << 16));         \
    if (h == 0 && wv == ((R_) & 7))                                          \
        gH[(R_) % 3] = *(const float2*)(xim + ((size_t)(lane >> 1) << 16)    \
                        + ((size_t)ROWCL(R_) << 8) + 128 + 2 * (lane & 1));  \
} while (0)

// convert + LDS-write input row R into slot R&7
#define CVTW(R_) do {                                                        \
    const float4 A_ = gA[(R_) % 3], B_ = gB[(R_) % 3];                       \
    unsigned int* d_ = &L[((R_) & 7) * SLOTW + (2 * wv + lhi) * ROWW + 4 * l31]; \
    *(uint4*)d_ = make_uint4(packpair(A_.x, B_.x), packpair(A_.y, B_.y),     \
                             packpair(A_.z, B_.z), packpair(A_.w, B_.w));    \
    if (h == 0 && wv == ((R_) & 7)) {                                        \
        const float2 V_ = gH[(R_) % 3];                                      \
        unsigned short* hp_ = (unsigned short*)&L[((R_) & 7) * SLOTW         \
                              + (lane >> 2) * ROWW + 128 + 2 * (lane & 1)]   \
                              + ((lane >> 1) & 1);                           \
        hp_[0] = f2bf(V_.x); hp_[2] = f2bf(V_.y);                            \
    }                                                                        \
} while (0)

#define MROW(P_, KY_) do {                                                   \
    if ((P_) - (KY_) >= 0 && (P_) - (KY_) <= 15) {                           \
        acc[(P_)-(KY_)][0] = MFMA(a0_.v, wf[(KY_)*3+0][0], acc[(P_)-(KY_)][0]); \
        acc[(P_)-(KY_)][0] = MFMA(a1_.v, wf[(KY_)*3+1][0], acc[(P_)-(KY_)][0]); \
        acc[(P_)-(KY_)][0] = MFMA(a2_.v, wf[(KY_)*3+2][0], acc[(P_)-(KY_)][0]); \
        acc[(P_)-(KY_)][1] = MFMA(a0_.v, wf[(KY_)*3+0][1], acc[(P_)-(KY_)][1]); \
        acc[(P_)-(KY_)][1] = MFMA(a1_.v, wf[(KY_)*3+1][1], acc[(P_)-(KY_)][1]); \
        acc[(P_)-(KY_)][1] = MFMA(a2_.v, wf[(KY_)*3+2][1], acc[(P_)-(KY_)][1]); \
    }                                                                        \
} while (0)

#define COMP(P_) do {                                                        \
    union { unsigned int u[4]; bf16x8 v; } a0_, a1_, a2_;                    \
    const unsigned int* sb_ = &L[((P_) & 7) * SLOTW + (g << 2) * ROWW        \
                                 + (wv << 4) + l15];                         \
    a0_.u[0] = sb_[0*ROWW+0]; a1_.u[0] = sb_[0*ROWW+1]; a2_.u[0] = sb_[0*ROWW+2]; \
    a0_.u[1] = sb_[1*ROWW+0]; a1_.u[1] = sb_[1*ROWW+1]; a2_.u[1] = sb_[1*ROWW+2]; \
    a0_.u[2] = sb_[2*ROWW+0]; a1_.u[2] = sb_[2*ROWW+1]; a2_.u[2] = sb_[2*ROWW+2]; \
    a0_.u[3] = sb_[3*ROWW+0]; a1_.u[3] = sb_[3*ROWW+1]; a2_.u[3] = sb_[3*ROWW+2]; \
    MROW(P_, 0); MROW(P_, 1); MROW(P_, 2);                                   \
} while (0)

// acc row R -> Lout[R&1][co][px]  (b128, conflict-free: 8 lanes per 4-bank grp)
#define OUTW(R_) do {                                                        \
    if ((R_) >= 0 && (R_) <= 15) {                                           \
        _Pragma("unroll")                                                    \
        for (int hh_ = 0; hh_ < 2; ++hh_) {                                  \
            const int co_ = (hh_ << 4) | l15;                                \
            float* dw_ = (float*)&L[LOUT0 + ((R_) & 1) * LOUTROW             \
                                    + co_ * ROWW + (wv << 4) + (g << 2)];    \
            *(f32x4*)dw_ = acc[R_][hh_];                                     \
        }                                                                    \
    }                                                                        \
} while (0)

// Lout row R -> global: wave wv stores co 4wv..4wv+3 as 512B contiguous runs
#define OUTRD(R_) do {                                                       \
    if ((R_) >= 0 && (R_) <= 15) {                                           \
        const int y_ = R0 + (R_);                                            \
        if (y_ < 254 && (h == 0 || lane < 63)) {                             \
            _Pragma("unroll")                                                \
            for (int k_ = 0; k_ < 4; ++k_) {                                 \
                const int co_ = (wv << 2) | k_;                              \
                const float2 v_ = *(const float2*)&L[LOUT0 + ((R_) & 1) * LOUTROW \
                                                     + co_ * ROWW + 2 * lane];    \
                *(float2*)(out + (size_t)((n << 5) | co_) * 64516            \
                           + y_ * 254 + (h << 7) + 2 * lane) = v_;           \
            }                                                                \
        }                                                                    \
    }                                                                        \
} while (0)

// Two-row step (P even): BAR A seals prev CVTW + prev OUTRD reads; MFMA burst;
// acc->Lout; input staging; prefetch; BAR B seals OUTW; contiguous stores.
#define STEP2(P_) do {                                                       \
    LGKMBAR;                                                                 \
    COMP(P_);                                                                \
    COMP((P_) + 1);                                                          \
    OUTW((P_) - 2);                                                          \
    OUTW((P_) - 1);                                                          \
    SCHED0;                                                                  \
    if ((P_) + 2 <= 17) CVTW((P_) + 2);                                      \
    if ((P_) + 3 <= 17) CVTW((P_) + 3);                                      \
    SCHED0;                                                                  \
    if ((P_) + 4 <= 17) ISSUE((P_) + 4);                                     \
    if ((P_) + 5 <= 17) ISSUE((P_) + 5);                                     \
    LGKMBAR;                                                                 \
    OUTRD((P_) - 2);                                                         \
    OUTRD((P_) - 1);                                                         \
} while (0)

__global__ __launch_bounds__(512, 1)
void fconv(const float* __restrict__ x, const float* __restrict__ w,
           float* __restrict__ out) {
    __shared__ unsigned int L[8 * SLOTW + 2 * LOUTROW];   // 101376 B

    const int tid  = threadIdx.x;
    const int bid  = blockIdx.x;
    const int o    = ((bid & 7) << 6) | (bid >> 3);   // XCD-chunked, bijective (512=8*64)
    const int n    = o >> 5;                          // image
    const int rb   = (o >> 1) & 15;                   // 16-row block
    const int h    = o & 1;                           // image half (128 px)
    const int wv   = tid >> 6;                        // wave 0..7 = 16-px strip
    const int lane = tid & 63;
    const int l15  = lane & 15;
    const int g    = lane >> 4;
    const int l31  = lane & 31;
    const int lhi  = lane >> 5;
    const int R0   = rb << 4;

    // ---- weights: stage ALL 9216 f32 -> LDS, then 18 reg B-frags
    #pragma unroll
    for (int k = 0; k < 18; ++k)
        ((float*)L)[tid + (k << 9)] = w[tid + (k << 9)];
    __syncthreads();
    bf16x8 wf[9][2];
    {
        const float* wl = (const float*)L;
        #pragma unroll
        for (int tap = 0; tap < 9; ++tap)
            #pragma unroll
            for (int hh = 0; hh < 2; ++hh) {
                union { unsigned short s[8]; bf16x8 v; } u;
                #pragma unroll
                for (int e = 0; e < 8; ++e)
                    u.s[e] = f2bf(wl[(hh * 16 + l15) * 288 + (8 * g + e) * 9 + tap]);
                wf[tap][hh] = u.v;
            }
    }
    __syncthreads();   // all frag reads done before L is reused as the ring

    // ---- h=1 never writes halo cols 128..131: zero them once (all 8 slots)
    if (h == 1) {
        const int s_ = tid >> 6, r_ = (tid >> 2) & 15, c_ = tid & 3;
        L[s_ * SLOTW + r_ * ROWW + 128 + c_] = 0u;   // 512 thr = 8x16x4 exactly
    }

    const float* xim = x + ((size_t)n << 21);
    const int    pA  = 4 * wv + 2 * lhi;              // even plane of the lane's pair
    const int    gpx = (h << 7) + 4 * l31;            // global px of lane's float4

    float4 gA[3], gB[3];
    float2 gH[3];

    f32x4 acc[16][2];
    #pragma unroll
    for (int r = 0; r < 16; ++r)
        #pragma unroll
        for (int hh = 0; hh < 2; ++hh) {
            f32x4 z = {0.f, 0.f, 0.f, 0.f};
            acc[r][hh] = z;
        }

    // ---- prologue: rows 0..3 issued (0,1 converted); reg-ring consume-before-
    //      overwrite: CVTW(0) precedes ISSUE(3) (both map to reg slot 0).
    ISSUE(0); ISSUE(1); ISSUE(2);
    SCHED0;
    CVTW(0);
    ISSUE(3);
    CVTW(1);
    // STEP2(0)'s opening LGKMBAR seals zero-init + CVTW(0,1) before COMP(0,1)

    // ---- 9 two-row steps (input rows R0..R0+17), fully unrolled
    STEP2(0);  STEP2(2);  STEP2(4);  STEP2(6);  STEP2(8);
    STEP2(10); STEP2(12); STEP2(14); STEP2(16);
}

extern "C" void kernel_launch(void* const* d_in, const int* in_sizes, int n_in,
                              void* d_out, int out_size, void* d_ws, size_t ws_size,
                              hipStream_t stream) {
    const float* x = (const float*)d_in[0];
    const float* w = (const float*)d_in[1];
    float* out     = (float*)d_out;
    hipLaunchKernelGGL(fconv, dim3(512), dim3(512), 0, stream, x, w, out);
}

// Round 16
// 55.886 us; speedup vs baseline: 1.0356x; 1.0356x over previous
//
#include <hip/hip_runtime.h>
#include <hip/hip_bf16.h>

// Fused 3x3 valid conv, fp32 NCHW in -> fp32 NCHW out, bf16 MFMA inside.
// x: (16,32,256,256) f32; w: (32,32,3,3) f32; out: (16,32,254,254) f32.
//
// FINAL (revert to R13, best measured: 56.03 us).
// Block = 512 thr (8 waves) = 128 out-px (half image width) x 16 out-rows x
// all 32 co. Two input rows per step, 9 lgkm-barriers. 8-slot LDS ring
// (leader writes slots (P+2/P+3)&7 while a post-barrier laggard still reads
// (P-2/P-1)&7 -- disjoint only mod 8). CVTW before ISSUE keeps reg rings
// 3-deep. Sync: s_waitcnt lgkmcnt(0) + s_barrier only (no vmcnt drain).
//
// Roofline evidence (R12-R15): VALU packing, barrier count, vmcnt schedule,
// and store granularity all null at ~56 us. Mandatory traffic 266 MB
// (134 R + 132 W fp32) -> ~50 us realistic mixed-stream floor; we're ~12% off
// with MFMA (9 us) fully hidden. Remaining gap = mixed-stream DRAM efficiency.

typedef __attribute__((ext_vector_type(8))) short bf16x8;
typedef __attribute__((ext_vector_type(4))) float f32x4;

#define MFMA(a,b,c) __builtin_amdgcn_mfma_f32_16x16x32_bf16((a),(b),(c),0,0,0)
#define SCHED0 __builtin_amdgcn_sched_barrier(0)
#define LGKMBAR asm volatile("s_waitcnt lgkmcnt(0)\n\ts_barrier" ::: "memory")

__device__ __forceinline__ unsigned short f2bf(float f) {
    unsigned int u = __float_as_uint(f);
    return (unsigned short)((u + 0x7FFFu + ((u >> 16) & 1u)) >> 16);   // RNE
}
__device__ __forceinline__ unsigned int packpair(float a, float b) {
    __hip_bfloat162 t = __float22bfloat162_rn(make_float2(a, b));      // v_cvt_pk_bf16_f32
    union { __hip_bfloat162 h; unsigned int u; } c;                    // lo=a (even ci), hi=b
    c.h = t;
    return c.u;
}

// LDS: slot = 16 ci2-rows x 132 u32 (528 B row) = 8448 B; 8 slots = 67584 B.
#define ROWW 132
#define SLOTW (16 * ROWW)

#define ROWCL(R_) ((R0 + (R_)) > 255 ? 255 : (R0 + (R_)))

// issue global loads for input row R (3-deep reg ring, literal %3)
#define ISSUE(R_) do {                                                       \
    const float* rp_ = xim + ((size_t)ROWCL(R_) << 8) + gpx;                 \
    gA[(R_) % 3] = *(const float4*)(rp_ + ((size_t)pA << 16));               \
    gB[(R_) % 3] = *(const float4*)(rp_ + (((size_t)pA + 1) << 16));         \
    if (h == 0 && wv == ((R_) & 7))                                          \
        gH[(R_) % 3] = *(const float2*)(xim + ((size_t)(lane >> 1) << 16)    \
                        + ((size_t)ROWCL(R_) << 8) + 128 + 2 * (lane & 1));  \
} while (0)

// convert + LDS-write input row R into slot R&7
#define CVTW(R_) do {                                                        \
    const float4 A_ = gA[(R_) % 3], B_ = gB[(R_) % 3];                       \
    unsigned int* d_ = &L[((R_) & 7) * SLOTW + (2 * wv + lhi) * ROWW + 4 * l31]; \
    *(uint4*)d_ = make_uint4(packpair(A_.x, B_.x), packpair(A_.y, B_.y),     \
                             packpair(A_.z, B_.z), packpair(A_.w, B_.w));    \
    if (h == 0 && wv == ((R_) & 7)) {                                        \
        const float2 V_ = gH[(R_) % 3];                                      \
        unsigned short* hp_ = (unsigned short*)&L[((R_) & 7) * SLOTW         \
                              + (lane >> 2) * ROWW + 128 + 2 * (lane & 1)]   \
                              + ((lane >> 1) & 1);                           \
        hp_[0] = f2bf(V_.x); hp_[2] = f2bf(V_.y);                            \
    }                                                                        \
} while (0)

#define MROW(P_, KY_) do {                                                   \
    if ((P_) - (KY_) >= 0 && (P_) - (KY_) <= 15) {                           \
        acc[(P_)-(KY_)][0] = MFMA(a0_.v, wf[(KY_)*3+0][0], acc[(P_)-(KY_)][0]); \
        acc[(P_)-(KY_)][0] = MFMA(a1_.v, wf[(KY_)*3+1][0], acc[(P_)-(KY_)][0]); \
        acc[(P_)-(KY_)][0] = MFMA(a2_.v, wf[(KY_)*3+2][0], acc[(P_)-(KY_)][0]); \
        acc[(P_)-(KY_)][1] = MFMA(a0_.v, wf[(KY_)*3+0][1], acc[(P_)-(KY_)][1]); \
        acc[(P_)-(KY_)][1] = MFMA(a1_.v, wf[(KY_)*3+1][1], acc[(P_)-(KY_)][1]); \
        acc[(P_)-(KY_)][1] = MFMA(a2_.v, wf[(KY_)*3+2][1], acc[(P_)-(KY_)][1]); \
    }                                                                        \
} while (0)

#define COMP(P_) do {                                                        \
    union { unsigned int u[4]; bf16x8 v; } a0_, a1_, a2_;                    \
    const unsigned int* sb_ = &L[((P_) & 7) * SLOTW + (g << 2) * ROWW        \
                                 + (wv << 4) + l15];                         \
    a0_.u[0] = sb_[0*ROWW+0]; a1_.u[0] = sb_[0*ROWW+1]; a2_.u[0] = sb_[0*ROWW+2]; \
    a0_.u[1] = sb_[1*ROWW+0]; a1_.u[1] = sb_[1*ROWW+1]; a2_.u[1] = sb_[1*ROWW+2]; \
    a0_.u[2] = sb_[2*ROWW+0]; a1_.u[2] = sb_[2*ROWW+1]; a2_.u[2] = sb_[2*ROWW+2]; \
    a0_.u[3] = sb_[3*ROWW+0]; a1_.u[3] = sb_[3*ROWW+1]; a2_.u[3] = sb_[3*ROWW+2]; \
    MROW(P_, 0); MROW(P_, 1); MROW(P_, 2);                                   \
} while (0)

#define STORE(R_) do {                                                       \
    if ((R_) >= 0 && (R_) <= 15) {                                           \
        const int y_ = R0 + (R_);                                            \
        if (y_ < 254) {                                                      \
            const int xo_ = (h << 7) + (wv << 4) + (g << 2);                 \
            _Pragma("unroll")                                                \
            for (int hh_ = 0; hh_ < 2; ++hh_) {                              \
                const f32x4 v_ = acc[R_][hh_];                               \
                float* p_ = out + (size_t)((n << 5) | (hh_ << 4) | l15) * 64516 \
                          + y_ * 254 + xo_;                                  \
                if (xo_ + 3 < 254) {                                         \
                    *(float2*)p_       = make_float2(v_[0], v_[1]);          \
                    *(float2*)(p_ + 2) = make_float2(v_[2], v_[3]);          \
                } else if (xo_ + 1 < 254) {        /* xo==252: px 252,253 */ \
                    *(float2*)p_ = make_float2(v_[0], v_[1]);                \
                }                                                            \
            }                                                                \
        }                                                                    \
    }                                                                        \
} while (0)

// Two-row step (P even). CVTW first (keeps reg rings 3-deep), then ISSUE,
// one lgkm barrier, two COMPs, two STOREs.
#define STEP2(P_) do {                                                       \
    if ((P_) + 2 <= 17) CVTW((P_) + 2);                                      \
    if ((P_) + 3 <= 17) CVTW((P_) + 3);                                      \
    SCHED0;                                                                  \
    if ((P_) + 4 <= 17) ISSUE((P_) + 4);                                     \
    if ((P_) + 5 <= 17) ISSUE((P_) + 5);                                     \
    LGKMBAR;                                                                 \
    COMP(P_);                                                                \
    COMP((P_) + 1);                                                          \
    STORE((P_) - 2);                                                         \
    STORE((P_) - 1);                                                         \
} while (0)

__global__ __launch_bounds__(512, 2)
void fconv(const float* __restrict__ x, const float* __restrict__ w,
           float* __restrict__ out) {
    __shared__ unsigned int L[8 * SLOTW];          // 67584 B (weights use 36864)

    const int tid  = threadIdx.x;
    const int bid  = blockIdx.x;
    const int o    = ((bid & 7) << 6) | (bid >> 3);   // XCD-chunked, bijective (512=8*64)
    const int n    = o >> 5;                          // image
    const int rb   = (o >> 1) & 15;                   // 16-row block
    const int h    = o & 1;                           // image half (128 px)
    const int wv   = tid >> 6;                        // wave 0..7 = 16-px strip
    const int lane = tid & 63;
    const int l15  = lane & 15;
    const int g    = lane >> 4;
    const int l31  = lane & 31;
    const int lhi  = lane >> 5;
    const int R0   = rb << 4;

    // ---- weights: stage ALL 9216 f32 -> LDS, then 18 reg B-frags
    #pragma unroll
    for (int k = 0; k < 18; ++k)
        ((float*)L)[tid + (k << 9)] = w[tid + (k << 9)];
    __syncthreads();
    bf16x8 wf[9][2];
    {
        const float* wl = (const float*)L;
        #pragma unroll
        for (int tap = 0; tap < 9; ++tap)
            #pragma unroll
            for (int hh = 0; hh < 2; ++hh) {
                union { unsigned short s[8]; bf16x8 v; } u;
                #pragma unroll
                for (int e = 0; e < 8; ++e)
                    u.s[e] = f2bf(wl[(hh * 16 + l15) * 288 + (8 * g + e) * 9 + tap]);
                wf[tap][hh] = u.v;
            }
    }
    __syncthreads();   // all frag reads done before L is reused as the ring

    // ---- h=1 never writes halo cols 128..131: zero them once (all 8 slots)
    if (h == 1) {
        const int s_ = tid >> 6, r_ = (tid >> 2) & 15, c_ = tid & 3;
        L[s_ * SLOTW + r_ * ROWW + 128 + c_] = 0u;   // 512 thr = 8x16x4 exactly
    }

    const float* xim = x + ((size_t)n << 21);
    const int    pA  = 4 * wv + 2 * lhi;              // even plane of the lane's pair
    const int    gpx = (h << 7) + 4 * l31;            // global px of lane's float4

    float4 gA[3], gB[3];
    float2 gH[3];

    f32x4 acc[16][2];
    #pragma unroll
    for (int r = 0; r < 16; ++r)
        #pragma unroll
        for (int hh = 0; hh < 2; ++hh) {
            f32x4 z = {0.f, 0.f, 0.f, 0.f};
            acc[r][hh] = z;
        }

    // ---- prologue: rows 0..2 issued; rows 0,1 into LDS; row 3 issued late
    ISSUE(0); ISSUE(1); ISSUE(2);
    SCHED0;
    CVTW(0); CVTW(1);
    ISSUE(3);                       // gA[0] reused after CVTW(0) consumed it
    LGKMBAR;                        // seals zero-init + CVTW(0,1) before COMP(0,1)

    // ---- 9 two-row steps (input rows R0..R0+17), fully unrolled
    STEP2(0);  STEP2(2);  STEP2(4);  STEP2(6);  STEP2(8);
    STEP2(10); STEP2(12); STEP2(14); STEP2(16);
}

extern "C" void kernel_launch(void* const* d_in, const int* in_sizes, int n_in,
                              void* d_out, int out_size, void* d_ws, size_t ws_size,
                              hipStream_t stream) {
    const float* x = (const float*)d_in[0];
    const float* w = (const float*)d_in[1];
    float* out     = (float*)d_out;
    hipLaunchKernelGGL(fconv, dim3(512), dim3(512), 0, stream, x, w, out);
}